// Round 11
// baseline (148.008 us; speedup 1.0000x reference)
//
#include <hip/hip_runtime.h>
#include <hip/hip_bf16.h>
#include <math.h>

#define NPTS 50000
#define BATCH 2
#define CIN 64
#define C2 64
#define KNN 16
#define NCELL 125
#define MTOT 800000

// wsf layout (floats):
// [16..1552)   PART1: pass-1 partials (b*3+c)*256 + s*8 + blk
// [2048..3584) PART2: pass-2 partials same indexing
// [4096..)     g[b][n][o] bf16 (12.8 MB)
// rel cache (19.2 MB) lives in d_out (fully overwritten by kmain afterwards).

using bf16x8 = __attribute__((ext_vector_type(8))) short;
using f32x4  = __attribute__((ext_vector_type(4))) float;

__device__ __forceinline__ float bflo(unsigned int v) { return __uint_as_float(v << 16); }
__device__ __forceinline__ float bfhi(unsigned int v) { return __uint_as_float(v & 0xffff0000u); }
__device__ __forceinline__ unsigned short f2bf(float f) {
    __hip_bfloat16 h = __float2bfloat16(f);
    return *(unsigned short*)&h;
}

__device__ __forceinline__ int to_cell32(float s) {
    float x = __fmul_rn(__fsub_rn(__fmul_rn(__fadd_rn(s, 1.0f), 5.0f), 1.0f), 0.5f);
    x = rintf(x);                       // half-to-even, matches np.round
    x = fminf(fmaxf(x, 0.0f), 4.0f);
    return (int)x;
}

// leaf bit-walk of numpy's pairwise split (n2 = n/2 - n/2%8), 8 levels, n=25000
__device__ __forceinline__ void leafwalk(int l, int& off, int& n) {
    off = 0; n = 25000;
    #pragma unroll
    for (int d = 7; d >= 0; --d) {
        int n2 = (n >> 1); n2 -= (n2 & 7);
        if ((l >> d) & 1) { off += n2; n -= n2; } else { n = n2; }
    }
}

// ---------------- K1: pw1 (c-merged, unroll-4), standalone ------------------
__global__ __launch_bounds__(256) void kpw1(const float* __restrict__ xyz,
                                            const int* __restrict__ knn,
                                            float* __restrict__ relc0,
                                            float* __restrict__ wsf) {
    __shared__ float lsum[32];
    int r8 = blockIdx.x;
    int s = r8 >> 3, blk = r8 & 7;
    int b = blockIdx.y;
    const float* xb = xyz + (size_t)b * 3 * NPTS;
    const int* kb = knn + (size_t)b * NPTS * KNN;
    float* relc = relc0 + (size_t)b * 3 * MTOT;
    int t = threadIdx.x;
    int l = blk * 32 + (t >> 3);
    int j = t & 7;
    int off, n;
    leafwalk(l, off, n);
    int base = s * 25000 + off;
    float r0 = 0.0f, r1 = 0.0f, r2 = 0.0f;
    int i = j;
    for (; i + 24 < n; i += 32) {
        int f0 = base + i, f1 = f0 + 8, f2 = f0 + 16, f3 = f0 + 24;
        int kk0 = f0 / NPTS, nn0 = f0 - kk0 * NPTS;
        int kk1 = f1 / NPTS, nn1 = f1 - kk1 * NPTS;
        int kk2 = f2 / NPTS, nn2 = f2 - kk2 * NPTS;
        int kk3 = f3 / NPTS, nn3 = f3 - kk3 * NPTS;
        int jA = kb[nn0 * KNN + kk0];
        int jB = kb[nn1 * KNN + kk1];
        int jC = kb[nn2 * KNN + kk2];
        int jD = kb[nn3 * KNN + kk3];
        float vA0 = __fsub_rn(xb[jA],            xb[nn0]);
        float vA1 = __fsub_rn(xb[NPTS + jA],     xb[NPTS + nn0]);
        float vA2 = __fsub_rn(xb[2 * NPTS + jA], xb[2 * NPTS + nn0]);
        float vB0 = __fsub_rn(xb[jB],            xb[nn1]);
        float vB1 = __fsub_rn(xb[NPTS + jB],     xb[NPTS + nn1]);
        float vB2 = __fsub_rn(xb[2 * NPTS + jB], xb[2 * NPTS + nn1]);
        float vC0 = __fsub_rn(xb[jC],            xb[nn2]);
        float vC1 = __fsub_rn(xb[NPTS + jC],     xb[NPTS + nn2]);
        float vC2 = __fsub_rn(xb[2 * NPTS + jC], xb[2 * NPTS + nn2]);
        float vD0 = __fsub_rn(xb[jD],            xb[nn3]);
        float vD1 = __fsub_rn(xb[NPTS + jD],     xb[NPTS + nn3]);
        float vD2 = __fsub_rn(xb[2 * NPTS + jD], xb[2 * NPTS + nn3]);
        relc[f0] = vA0; relc[MTOT + f0] = vA1; relc[2 * MTOT + f0] = vA2;
        relc[f1] = vB0; relc[MTOT + f1] = vB1; relc[2 * MTOT + f1] = vB2;
        relc[f2] = vC0; relc[MTOT + f2] = vC1; relc[2 * MTOT + f2] = vC2;
        relc[f3] = vD0; relc[MTOT + f3] = vD1; relc[2 * MTOT + f3] = vD2;
        r0 = __fadd_rn(r0, vA0); r1 = __fadd_rn(r1, vA1); r2 = __fadd_rn(r2, vA2);
        r0 = __fadd_rn(r0, vB0); r1 = __fadd_rn(r1, vB1); r2 = __fadd_rn(r2, vB2);
        r0 = __fadd_rn(r0, vC0); r1 = __fadd_rn(r1, vC1); r2 = __fadd_rn(r2, vC2);
        r0 = __fadd_rn(r0, vD0); r1 = __fadd_rn(r1, vD1); r2 = __fadd_rn(r2, vD2);
    }
    for (; i < n; i += 8) {
        int f = base + i;
        int kk = f / NPTS, nn = f - kk * NPTS;
        int jj = kb[nn * KNN + kk];
        float v0 = __fsub_rn(xb[jj],            xb[nn]);
        float v1 = __fsub_rn(xb[NPTS + jj],     xb[NPTS + nn]);
        float v2 = __fsub_rn(xb[2 * NPTS + jj], xb[2 * NPTS + nn]);
        relc[f] = v0; relc[MTOT + f] = v1; relc[2 * MTOT + f] = v2;
        r0 = __fadd_rn(r0, v0); r1 = __fadd_rn(r1, v1); r2 = __fadd_rn(r2, v2);
    }
    float a0 = __fadd_rn(r0, __shfl_xor(r0, 1));
    a0 = __fadd_rn(a0, __shfl_xor(a0, 2));
    a0 = __fadd_rn(a0, __shfl_xor(a0, 4));
    float a1 = __fadd_rn(r1, __shfl_xor(r1, 1));
    a1 = __fadd_rn(a1, __shfl_xor(a1, 2));
    a1 = __fadd_rn(a1, __shfl_xor(a1, 4));
    float a2 = __fadd_rn(r2, __shfl_xor(r2, 1));
    a2 = __fadd_rn(a2, __shfl_xor(a2, 2));
    a2 = __fadd_rn(a2, __shfl_xor(a2, 4));
    #pragma unroll
    for (int c = 0; c < 3; ++c) {
        float rc = (c == 0) ? a0 : ((c == 1) ? a1 : a2);
        __syncthreads();
        if (j == 0) lsum[t >> 3] = rc;
        __syncthreads();
        for (int m = 16; m >= 1; m >>= 1) {
            float v = 0.0f;
            if (t < m) v = __fadd_rn(lsum[2 * t], lsum[2 * t + 1]);
            __syncthreads();
            if (t < m) lsum[t] = v;
            __syncthreads();
        }
        if (t == 0) wsf[16 + ((size_t)(b * 3 + c) * 32 + s) * 8 + blk] = lsum[0];
    }
}

// ---------------- K2: MFMA GEMM (0..1563) + pw2 tail (1564..3099) -----------
__global__ __launch_bounds__(256) void kfuse2(const float* __restrict__ fea,
                                              const float* __restrict__ W,
                                              unsigned short* __restrict__ g,
                                              const float* __restrict__ relc0,
                                              float* __restrict__ wsf) {
    __shared__ unsigned short flds[64 * 72];      // 9216B; aliased by pw2 lsum
    int bx = blockIdx.x;
    int t = threadIdx.x;
    if (bx < 1564) {
        // ---- MFMA GEMM: g[b][n][o] = sum_c W[o][c]*fea[b][c][n] -> bf16 ----
        int b = (bx >= 782);
        int tile = bx - b * 782;
        int n0 = tile * 64;
        int nrem = NPTS - n0; if (nrem > 64) nrem = 64;
        const float* fb = fea + (size_t)b * CIN * NPTS;
        int j = t & 63, w = t >> 6;
        int lane = t & 63, li = lane & 15, gq = lane >> 4;
        // stage fea tile -> bf16 LDS [n][c], row stride 72 (16B-aligned reads)
        #pragma unroll
        for (int i = 0; i < 8; ++i) {
            int c = w * 2 + i * 8;
            float v0 = (j < nrem) ? fb[(size_t)c * NPTS + n0 + j] : 0.0f;
            float v1 = (j < nrem) ? fb[(size_t)(c + 1) * NPTS + n0 + j] : 0.0f;
            unsigned int pk = (unsigned int)f2bf(v0) | ((unsigned int)f2bf(v1) << 16);
            *(unsigned int*)&flds[j * 72 + c] = pk;
        }
        // W fragments (global direct, L1-hot): A[m][k], m=li, k=kh*32+gq*8+e
        bf16x8 af[4][2];
        #pragma unroll
        for (int mt = 0; mt < 4; ++mt)
            #pragma unroll
            for (int kh = 0; kh < 2; ++kh) {
                const float* wp = W + (mt * 16 + li) * CIN + kh * 32 + gq * 8;
                float4 wa = *(const float4*)wp;
                float4 wb = *(const float4*)(wp + 4);
                bf16x8 a;
                a[0] = (short)f2bf(wa.x); a[1] = (short)f2bf(wa.y);
                a[2] = (short)f2bf(wa.z); a[3] = (short)f2bf(wa.w);
                a[4] = (short)f2bf(wb.x); a[5] = (short)f2bf(wb.y);
                a[6] = (short)f2bf(wb.z); a[7] = (short)f2bf(wb.w);
                af[mt][kh] = a;
            }
        __syncthreads();
        f32x4 acc[4];
        #pragma unroll
        for (int mt = 0; mt < 4; ++mt) acc[mt] = (f32x4){0.f, 0.f, 0.f, 0.f};
        #pragma unroll
        for (int kh = 0; kh < 2; ++kh) {
            bf16x8 bfv = *(const bf16x8*)&flds[(w * 16 + li) * 72 + kh * 32 + gq * 8];
            #pragma unroll
            for (int mt = 0; mt < 4; ++mt)
                acc[mt] = __builtin_amdgcn_mfma_f32_16x16x32_bf16(af[mt][kh], bfv,
                                                                  acc[mt], 0, 0, 0);
        }
        // D[row=o][col=n]: col=li, row=gq*4+reg (within mt*16 tile)
        int nloc = w * 16 + li;
        if (nloc < nrem) {
            unsigned short* gr = g + ((size_t)b * NPTS + n0 + nloc) * C2;
            #pragma unroll
            for (int mt = 0; mt < 4; ++mt) {
                int ob = mt * 16 + gq * 4;
                uint2 pk;
                pk.x = (unsigned int)f2bf(acc[mt][0]) | ((unsigned int)f2bf(acc[mt][1]) << 16);
                pk.y = (unsigned int)f2bf(acc[mt][2]) | ((unsigned int)f2bf(acc[mt][3]) << 16);
                *(uint2*)(gr + ob) = pk;
            }
        }
    } else {
        // ---- pw2 role (coord-split, inline bit-exact mean, unroll-4) ------
        float* lsum = (float*)flds;
        int pid = bx - 1564;                 // 0..1535
        int b = pid / 768, rem = pid - b * 768;
        int c = rem >> 8, r8 = rem & 255;
        int s = r8 >> 3, blk = r8 & 7;

        const float* P = wsf + 16 + (size_t)(b * 3 + c) * 256;
        if (t < 32) {
            const float* q = P + t * 8;
            float a  = __fadd_rn(__fadd_rn(q[0], q[1]), __fadd_rn(q[2], q[3]));
            float b2 = __fadd_rn(__fadd_rn(q[4], q[5]), __fadd_rn(q[6], q[7]));
            lsum[t] = __fadd_rn(a, b2);
        }
        __syncthreads();
        for (int m = 16; m >= 1; m >>= 1) {
            float v = 0.0f;
            if (t < m) v = __fadd_rn(lsum[2 * t], lsum[2 * t + 1]);
            __syncthreads();
            if (t < m) lsum[t] = v;
            __syncthreads();
        }
        if (t == 0) lsum[1] = lsum[0] / 800000.0f;
        __syncthreads();
        float mean = lsum[1];
        __syncthreads();

        const float* relc = relc0 + (size_t)(b * 3 + c) * MTOT;
        int l = blk * 32 + (t >> 3);
        int j = t & 7;
        int off, n;
        leafwalk(l, off, n);
        int base = s * 25000 + off;
        float r = 0.0f;
        int i = j;
        for (; i + 24 < n; i += 32) {
            float a0 = relc[base + i];
            float a1 = relc[base + i + 8];
            float a2 = relc[base + i + 16];
            float a3 = relc[base + i + 24];
            float d0 = __fsub_rn(a0, mean);
            float d1 = __fsub_rn(a1, mean);
            float d2 = __fsub_rn(a2, mean);
            float d3 = __fsub_rn(a3, mean);
            r = __fadd_rn(r, __fmul_rn(d0, d0));
            r = __fadd_rn(r, __fmul_rn(d1, d1));
            r = __fadd_rn(r, __fmul_rn(d2, d2));
            r = __fadd_rn(r, __fmul_rn(d3, d3));
        }
        for (; i < n; i += 8) {
            float d0 = __fsub_rn(relc[base + i], mean);
            r = __fadd_rn(r, __fmul_rn(d0, d0));
        }
        float a = __fadd_rn(r, __shfl_xor(r, 1));
        a = __fadd_rn(a, __shfl_xor(a, 2));
        a = __fadd_rn(a, __shfl_xor(a, 4));
        if (j == 0) lsum[t >> 3] = a;
        __syncthreads();
        for (int m = 16; m >= 1; m >>= 1) {
            float v = 0.0f;
            if (t < m) v = __fadd_rn(lsum[2 * t], lsum[2 * t + 1]);
            __syncthreads();
            if (t < m) lsum[t] = v;
            __syncthreads();
        }
        if (t == 0) wsf[2048 + ((size_t)(b * 3 + c) * 32 + s) * 8 + blk] = lsum[0];
    }
}

// ---------------- K3: kmain — half-wave uint gathers, 6/CU ------------------
__global__ __launch_bounds__(256, 6) void kmain(const float* __restrict__ xyz,
                                                const int* __restrict__ idx,
                                                const float* __restrict__ cb,
                                                const float* __restrict__ dw,
                                                const unsigned short* __restrict__ g,
                                                const float* __restrict__ wsf,
                                                float* __restrict__ out) {
    __shared__ unsigned int  dwp[NCELL * 32];    // 16000B
    __shared__ unsigned char celllds[64 * KNN];  // 1024B
    __shared__ float         ctr[3][64];         // 768B
    __shared__ float         res[128 * 17];      // 8704B  (l3 tree aliases res)
    int b = blockIdx.y;
    int n0 = blockIdx.x * 64;
    int t = threadIdx.x;
    int nrem = NPTS - n0; if (nrem > 64) nrem = 64;

    float* l3 = res;
    if (t < 96) {
        int c = t >> 5, l = t & 31;
        const float* q = wsf + 2048 + (size_t)(b * 3 + c) * 256 + l * 8;
        float a  = __fadd_rn(__fadd_rn(q[0], q[1]), __fadd_rn(q[2], q[3]));
        float b2 = __fadd_rn(__fadd_rn(q[4], q[5]), __fadd_rn(q[6], q[7]));
        l3[c * 32 + l] = __fadd_rn(a, b2);
    }
    __syncthreads();
    for (int m = 16; m >= 1; m >>= 1) {
        float v = 0.0f;
        int c = t >> 5, l = t & 31;
        if (t < 96 && l < m) v = __fadd_rn(l3[c * 32 + 2 * l], l3[c * 32 + 2 * l + 1]);
        __syncthreads();
        if (t < 96 && l < m) l3[c * 32 + l] = v;
        __syncthreads();
    }
    float dn0 = __fmul_rn(4.0f, sqrtf(l3[0]  / 799999.0f));
    float dn1 = __fmul_rn(4.0f, sqrtf(l3[32] / 799999.0f));
    float dn2 = __fmul_rn(4.0f, sqrtf(l3[64] / 799999.0f));
    __syncthreads();

    for (int i = t; i < NCELL * 32; i += 256) {
        int cell = i >> 5, u = i & 31;
        unsigned int p0 = f2bf(dw[(2 * u)     * NCELL + cell]);
        unsigned int p1 = f2bf(dw[(2 * u + 1) * NCELL + cell]);
        dwp[i] = p0 | (p1 << 16);
    }
    const float* xb = xyz + (size_t)b * 3 * NPTS;
    if (t < 192) {
        int c = t >> 6, jx = t & 63;
        if (jx < nrem) ctr[c][jx] = xb[c * NPTS + n0 + jx];
    }
    const int* ib = idx + ((size_t)b * NPTS + n0) * KNN;
    __syncthreads();

    for (int i = t; i < nrem * KNN; i += 256) {
        int p = i >> 4;
        int jx = ib[i];
        float sx = __fsub_rn(xb[jx],            ctr[0][p]) / dn0;
        float sy = __fsub_rn(xb[NPTS + jx],     ctr[1][p]) / dn1;
        float sz = __fsub_rn(xb[2 * NPTS + jx], ctr[2][p]) / dn2;
        celllds[i] = (unsigned char)((to_cell32(sz) * 5 + to_cell32(sy)) * 5 + to_cell32(sx));
    }
    __syncthreads();

    int w = t >> 6, h = (t >> 5) & 1, u = t & 31;
    int o0 = 2 * u, o1 = 2 * u + 1;
    float cb0 = cb[o0], cb1 = cb[o1];
    const unsigned short* gbp = g + (size_t)b * NPTS * C2;
    float* ob = out + (size_t)b * 128 * NPTS;

    #pragma unroll 1
    for (int chunk = 0; chunk < 4; ++chunk) {
        int pbase = chunk * 16;
        #pragma unroll
        for (int i = 0; i < 2; ++i) {
            int p = pbase + i * 8 + w * 2 + h;
            if (p < nrem) {
                const int* row = ib + p * KNN;
                unsigned int gnv = *(const unsigned int*)(gbp + (size_t)(n0 + p) * C2 + o0);
                float gn0 = bflo(gnv), gn1 = bfhi(gnv);
                int cell0 = celllds[p * KNN];
                unsigned int dp0 = dwp[cell0 * 32 + u];
                float k00 = bflo(dp0), k01 = bfhi(dp0);
                float ws0 = 0, ws1 = 0, gs0 = 0, gs1 = 0, sk0 = 0, sk1 = 0;
                #pragma unroll
                for (int k = 1; k < 16; ++k) {
                    int jj   = row[k];                         // broadcast, L1-hot
                    int cell = celllds[p * KNN + k];
                    unsigned int gv = *(const unsigned int*)(gbp + (size_t)jj * C2 + o0);
                    unsigned int dp = dwp[cell * 32 + u];
                    float g0 = bflo(gv), g1 = bfhi(gv);
                    float kw0 = bflo(dp), kw1 = bfhi(dp);
                    ws0 = fmaf(kw0, g0, ws0); ws1 = fmaf(kw1, g1, ws1);
                    gs0 += g0; gs1 += g1; sk0 += kw0; sk1 += kw1;
                }
                int pl = p & 15;
                res[o0 * 17 + pl]        = cb0 * (k00 + sk0) + gn0 * (k00 - sk0) + ws0;
                res[o1 * 17 + pl]        = cb1 * (k01 + sk1) + gn1 * (k01 - sk1) + ws1;
                res[(64 + o0) * 17 + pl] = cb0 + 0.0625f * (gs0 - 14.0f * gn0);
                res[(64 + o1) * 17 + pl] = cb1 + 0.0625f * (gs1 - 14.0f * gn1);
            }
        }
        __syncthreads();
        int rl = t >> 4;
        int jn = t & 15;
        int ncol = nrem - pbase; if (ncol > 16) ncol = 16;
        if (jn < ncol) {
            for (int r2 = rl; r2 < 128; r2 += 16)
                ob[(size_t)r2 * NPTS + n0 + pbase + jn] = res[r2 * 17 + jn];
        }
        __syncthreads();
    }
}

extern "C" void kernel_launch(void* const* d_in, const int* in_sizes, int n_in,
                              void* d_out, int out_size, void* d_ws, size_t ws_size,
                              hipStream_t stream) {
    const float* xyz   = (const float*)d_in[0];
    const float* fea   = (const float*)d_in[1];
    const int*   knn   = (const int*)d_in[2];
    const float* convw = (const float*)d_in[3];
    const float* convb = (const float*)d_in[4];
    const float* convdw= (const float*)d_in[5];
    float* out = (float*)d_out;
    float* wsf = (float*)d_ws;
    unsigned short* g = (unsigned short*)(wsf + 4096);
    float* relc = out;               // 4.8M floats scratch, fully overwritten by kmain

    kpw1  <<<dim3(256, BATCH), 256, 0, stream>>>(xyz, knn, relc, wsf);
    kfuse2<<<1564 + 1536, 256, 0, stream>>>(fea, convw, g, relc, wsf);
    kmain <<<dim3(782, BATCH), 256, 0, stream>>>(xyz, knn, convb, convdw, g, wsf, out);
}

// Round 12
// 121.502 us; speedup vs baseline: 1.2181x; 1.2181x over previous
//
#include <hip/hip_runtime.h>
#include <hip/hip_bf16.h>
#include <math.h>

#define NPTS 50000
#define BATCH 2
#define CIN 64
#define C2 64
#define KNN 16
#define NCELL 125
#define MTOT 800000

// wsf layout (floats):
// [16..1552)   PART1: pass-1 partials (b*3+c)*256 + s*8 + blk
// [2048..3584) PART2: pass-2 partials same indexing
// [8192..12192) packed dw table: 4000 uints (dwp[cell*32+u] = bf16 pair 2u,2u+1)
// [16384..)    g[b][n][o] bf16 (12.8 MB)
// rel cache (19.2 MB) lives in d_out (fully overwritten by kmain afterwards).

using bf16x8 = __attribute__((ext_vector_type(8))) short;
using f32x4  = __attribute__((ext_vector_type(4))) float;

__device__ __forceinline__ float bflo(unsigned int v) { return __uint_as_float(v << 16); }
__device__ __forceinline__ float bfhi(unsigned int v) { return __uint_as_float(v & 0xffff0000u); }
__device__ __forceinline__ unsigned short f2bf(float f) {
    __hip_bfloat16 h = __float2bfloat16(f);
    return *(unsigned short*)&h;
}

__device__ __forceinline__ int to_cell32(float s) {
    float x = __fmul_rn(__fsub_rn(__fmul_rn(__fadd_rn(s, 1.0f), 5.0f), 1.0f), 0.5f);
    x = rintf(x);                       // half-to-even, matches np.round
    x = fminf(fmaxf(x, 0.0f), 4.0f);
    return (int)x;
}

// leaf bit-walk of numpy's pairwise split (n2 = n/2 - n/2%8), 8 levels, n=25000
__device__ __forceinline__ void leafwalk(int l, int& off, int& n) {
    off = 0; n = 25000;
    #pragma unroll
    for (int d = 7; d >= 0; --d) {
        int n2 = (n >> 1); n2 -= (n2 & 7);
        if ((l >> d) & 1) { off += n2; n -= n2; } else { n = n2; }
    }
}

// ---------------- K1: pw1 (c-merged, unroll-4), standalone ------------------
__global__ __launch_bounds__(256) void kpw1(const float* __restrict__ xyz,
                                            const int* __restrict__ knn,
                                            float* __restrict__ relc0,
                                            float* __restrict__ wsf) {
    __shared__ float lsum[32];
    int r8 = blockIdx.x;
    int s = r8 >> 3, blk = r8 & 7;
    int b = blockIdx.y;
    const float* xb = xyz + (size_t)b * 3 * NPTS;
    const int* kb = knn + (size_t)b * NPTS * KNN;
    float* relc = relc0 + (size_t)b * 3 * MTOT;
    int t = threadIdx.x;
    int l = blk * 32 + (t >> 3);
    int j = t & 7;
    int off, n;
    leafwalk(l, off, n);
    int base = s * 25000 + off;
    float r0 = 0.0f, r1 = 0.0f, r2 = 0.0f;
    int i = j;
    for (; i + 24 < n; i += 32) {
        int f0 = base + i, f1 = f0 + 8, f2 = f0 + 16, f3 = f0 + 24;
        int kk0 = f0 / NPTS, nn0 = f0 - kk0 * NPTS;
        int kk1 = f1 / NPTS, nn1 = f1 - kk1 * NPTS;
        int kk2 = f2 / NPTS, nn2 = f2 - kk2 * NPTS;
        int kk3 = f3 / NPTS, nn3 = f3 - kk3 * NPTS;
        int jA = kb[nn0 * KNN + kk0];
        int jB = kb[nn1 * KNN + kk1];
        int jC = kb[nn2 * KNN + kk2];
        int jD = kb[nn3 * KNN + kk3];
        float vA0 = __fsub_rn(xb[jA],            xb[nn0]);
        float vA1 = __fsub_rn(xb[NPTS + jA],     xb[NPTS + nn0]);
        float vA2 = __fsub_rn(xb[2 * NPTS + jA], xb[2 * NPTS + nn0]);
        float vB0 = __fsub_rn(xb[jB],            xb[nn1]);
        float vB1 = __fsub_rn(xb[NPTS + jB],     xb[NPTS + nn1]);
        float vB2 = __fsub_rn(xb[2 * NPTS + jB], xb[2 * NPTS + nn1]);
        float vC0 = __fsub_rn(xb[jC],            xb[nn2]);
        float vC1 = __fsub_rn(xb[NPTS + jC],     xb[NPTS + nn2]);
        float vC2 = __fsub_rn(xb[2 * NPTS + jC], xb[2 * NPTS + nn2]);
        float vD0 = __fsub_rn(xb[jD],            xb[nn3]);
        float vD1 = __fsub_rn(xb[NPTS + jD],     xb[NPTS + nn3]);
        float vD2 = __fsub_rn(xb[2 * NPTS + jD], xb[2 * NPTS + nn3]);
        relc[f0] = vA0; relc[MTOT + f0] = vA1; relc[2 * MTOT + f0] = vA2;
        relc[f1] = vB0; relc[MTOT + f1] = vB1; relc[2 * MTOT + f1] = vB2;
        relc[f2] = vC0; relc[MTOT + f2] = vC1; relc[2 * MTOT + f2] = vC2;
        relc[f3] = vD0; relc[MTOT + f3] = vD1; relc[2 * MTOT + f3] = vD2;
        r0 = __fadd_rn(r0, vA0); r1 = __fadd_rn(r1, vA1); r2 = __fadd_rn(r2, vA2);
        r0 = __fadd_rn(r0, vB0); r1 = __fadd_rn(r1, vB1); r2 = __fadd_rn(r2, vB2);
        r0 = __fadd_rn(r0, vC0); r1 = __fadd_rn(r1, vC1); r2 = __fadd_rn(r2, vC2);
        r0 = __fadd_rn(r0, vD0); r1 = __fadd_rn(r1, vD1); r2 = __fadd_rn(r2, vD2);
    }
    for (; i < n; i += 8) {
        int f = base + i;
        int kk = f / NPTS, nn = f - kk * NPTS;
        int jj = kb[nn * KNN + kk];
        float v0 = __fsub_rn(xb[jj],            xb[nn]);
        float v1 = __fsub_rn(xb[NPTS + jj],     xb[NPTS + nn]);
        float v2 = __fsub_rn(xb[2 * NPTS + jj], xb[2 * NPTS + nn]);
        relc[f] = v0; relc[MTOT + f] = v1; relc[2 * MTOT + f] = v2;
        r0 = __fadd_rn(r0, v0); r1 = __fadd_rn(r1, v1); r2 = __fadd_rn(r2, v2);
    }
    float a0 = __fadd_rn(r0, __shfl_xor(r0, 1));
    a0 = __fadd_rn(a0, __shfl_xor(a0, 2));
    a0 = __fadd_rn(a0, __shfl_xor(a0, 4));
    float a1 = __fadd_rn(r1, __shfl_xor(r1, 1));
    a1 = __fadd_rn(a1, __shfl_xor(a1, 2));
    a1 = __fadd_rn(a1, __shfl_xor(a1, 4));
    float a2 = __fadd_rn(r2, __shfl_xor(r2, 1));
    a2 = __fadd_rn(a2, __shfl_xor(a2, 2));
    a2 = __fadd_rn(a2, __shfl_xor(a2, 4));
    #pragma unroll
    for (int c = 0; c < 3; ++c) {
        float rc = (c == 0) ? a0 : ((c == 1) ? a1 : a2);
        __syncthreads();
        if (j == 0) lsum[t >> 3] = rc;
        __syncthreads();
        for (int m = 16; m >= 1; m >>= 1) {
            float v = 0.0f;
            if (t < m) v = __fadd_rn(lsum[2 * t], lsum[2 * t + 1]);
            __syncthreads();
            if (t < m) lsum[t] = v;
            __syncthreads();
        }
        if (t == 0) wsf[16 + ((size_t)(b * 3 + c) * 32 + s) * 8 + blk] = lsum[0];
    }
}

// ---------------- K2: MFMA GEMM (0..1563) + pw2 (1564..3099) + dwpack -------
__global__ __launch_bounds__(256) void kfuse2(const float* __restrict__ fea,
                                              const float* __restrict__ W,
                                              const float* __restrict__ dw,
                                              unsigned short* __restrict__ g,
                                              const float* __restrict__ relc0,
                                              float* __restrict__ wsf) {
    __shared__ unsigned short flds[64 * 72];      // 9216B; aliased by pw2 lsum
    int bx = blockIdx.x;
    int t = threadIdx.x;
    if (bx < 1564) {
        // ---- MFMA GEMM: g[b][n][o] = sum_c W[o][c]*fea[b][c][n] -> bf16 ----
        int b = (bx >= 782);
        int tile = bx - b * 782;
        int n0 = tile * 64;
        int nrem = NPTS - n0; if (nrem > 64) nrem = 64;
        const float* fb = fea + (size_t)b * CIN * NPTS;
        int j = t & 63, w = t >> 6;
        int lane = t & 63, li = lane & 15, gq = lane >> 4;
        #pragma unroll
        for (int i = 0; i < 8; ++i) {
            int c = w * 2 + i * 8;
            float v0 = (j < nrem) ? fb[(size_t)c * NPTS + n0 + j] : 0.0f;
            float v1 = (j < nrem) ? fb[(size_t)(c + 1) * NPTS + n0 + j] : 0.0f;
            unsigned int pk = (unsigned int)f2bf(v0) | ((unsigned int)f2bf(v1) << 16);
            *(unsigned int*)&flds[j * 72 + c] = pk;
        }
        bf16x8 af[4][2];
        #pragma unroll
        for (int mt = 0; mt < 4; ++mt)
            #pragma unroll
            for (int kh = 0; kh < 2; ++kh) {
                const float* wp = W + (mt * 16 + li) * CIN + kh * 32 + gq * 8;
                float4 wa = *(const float4*)wp;
                float4 wb = *(const float4*)(wp + 4);
                bf16x8 a;
                a[0] = (short)f2bf(wa.x); a[1] = (short)f2bf(wa.y);
                a[2] = (short)f2bf(wa.z); a[3] = (short)f2bf(wa.w);
                a[4] = (short)f2bf(wb.x); a[5] = (short)f2bf(wb.y);
                a[6] = (short)f2bf(wb.z); a[7] = (short)f2bf(wb.w);
                af[mt][kh] = a;
            }
        __syncthreads();
        f32x4 acc[4];
        #pragma unroll
        for (int mt = 0; mt < 4; ++mt) acc[mt] = (f32x4){0.f, 0.f, 0.f, 0.f};
        #pragma unroll
        for (int kh = 0; kh < 2; ++kh) {
            bf16x8 bfv = *(const bf16x8*)&flds[(w * 16 + li) * 72 + kh * 32 + gq * 8];
            #pragma unroll
            for (int mt = 0; mt < 4; ++mt)
                acc[mt] = __builtin_amdgcn_mfma_f32_16x16x32_bf16(af[mt][kh], bfv,
                                                                  acc[mt], 0, 0, 0);
        }
        int nloc = w * 16 + li;
        if (nloc < nrem) {
            unsigned short* gr = g + ((size_t)b * NPTS + n0 + nloc) * C2;
            #pragma unroll
            for (int mt = 0; mt < 4; ++mt) {
                int ob = mt * 16 + gq * 4;
                uint2 pk;
                pk.x = (unsigned int)f2bf(acc[mt][0]) | ((unsigned int)f2bf(acc[mt][1]) << 16);
                pk.y = (unsigned int)f2bf(acc[mt][2]) | ((unsigned int)f2bf(acc[mt][3]) << 16);
                *(uint2*)(gr + ob) = pk;
            }
        }
    } else if (bx < 3100) {
        // ---- pw2 role (coord-split, inline bit-exact mean, unroll-4) ------
        float* lsum = (float*)flds;
        int pid = bx - 1564;                 // 0..1535
        int b = pid / 768, rem = pid - b * 768;
        int c = rem >> 8, r8 = rem & 255;
        int s = r8 >> 3, blk = r8 & 7;

        const float* P = wsf + 16 + (size_t)(b * 3 + c) * 256;
        if (t < 32) {
            const float* q = P + t * 8;
            float a  = __fadd_rn(__fadd_rn(q[0], q[1]), __fadd_rn(q[2], q[3]));
            float b2 = __fadd_rn(__fadd_rn(q[4], q[5]), __fadd_rn(q[6], q[7]));
            lsum[t] = __fadd_rn(a, b2);
        }
        __syncthreads();
        for (int m = 16; m >= 1; m >>= 1) {
            float v = 0.0f;
            if (t < m) v = __fadd_rn(lsum[2 * t], lsum[2 * t + 1]);
            __syncthreads();
            if (t < m) lsum[t] = v;
            __syncthreads();
        }
        if (t == 0) lsum[1] = lsum[0] / 800000.0f;
        __syncthreads();
        float mean = lsum[1];
        __syncthreads();

        const float* relc = relc0 + (size_t)(b * 3 + c) * MTOT;
        int l = blk * 32 + (t >> 3);
        int j = t & 7;
        int off, n;
        leafwalk(l, off, n);
        int base = s * 25000 + off;
        float r = 0.0f;
        int i = j;
        for (; i + 24 < n; i += 32) {
            float a0 = relc[base + i];
            float a1 = relc[base + i + 8];
            float a2 = relc[base + i + 16];
            float a3 = relc[base + i + 24];
            float d0 = __fsub_rn(a0, mean);
            float d1 = __fsub_rn(a1, mean);
            float d2 = __fsub_rn(a2, mean);
            float d3 = __fsub_rn(a3, mean);
            r = __fadd_rn(r, __fmul_rn(d0, d0));
            r = __fadd_rn(r, __fmul_rn(d1, d1));
            r = __fadd_rn(r, __fmul_rn(d2, d2));
            r = __fadd_rn(r, __fmul_rn(d3, d3));
        }
        for (; i < n; i += 8) {
            float d0 = __fsub_rn(relc[base + i], mean);
            r = __fadd_rn(r, __fmul_rn(d0, d0));
        }
        float a = __fadd_rn(r, __shfl_xor(r, 1));
        a = __fadd_rn(a, __shfl_xor(a, 2));
        a = __fadd_rn(a, __shfl_xor(a, 4));
        if (j == 0) lsum[t >> 3] = a;
        __syncthreads();
        for (int m = 16; m >= 1; m >>= 1) {
            float v = 0.0f;
            if (t < m) v = __fadd_rn(lsum[2 * t], lsum[2 * t + 1]);
            __syncthreads();
            if (t < m) lsum[t] = v;
            __syncthreads();
        }
        if (t == 0) wsf[2048 + ((size_t)(b * 3 + c) * 32 + s) * 8 + blk] = lsum[0];
    } else {
        // ---- dw pack role: 16 blocks, 4000 entries total -------------------
        unsigned int* gdwp = (unsigned int*)(wsf + 8192);
        int i0 = (bx - 3100) * 250;
        for (int i = i0 + t; i < i0 + 250; i += 256) {
            int cell = i >> 5, u = i & 31;
            unsigned int p0 = f2bf(dw[(2 * u)     * NCELL + cell]);
            unsigned int p1 = f2bf(dw[(2 * u + 1) * NCELL + cell]);
            gdwp[i] = p0 | (p1 << 16);
        }
    }
}

// ---------------- K3: kmain — half-wave uint gathers, 6/CU, unroll-1 --------
__global__ __launch_bounds__(256, 6) void kmain(const float* __restrict__ xyz,
                                                const int* __restrict__ idx,
                                                const float* __restrict__ cb,
                                                const unsigned short* __restrict__ g,
                                                const float* __restrict__ wsf,
                                                float* __restrict__ out) {
    __shared__ unsigned int  dwp[NCELL * 32];    // 16000B
    __shared__ unsigned char celllds[64 * KNN];  // 1024B
    __shared__ float         ctr[3][64];         // 768B
    __shared__ float         res[128 * 17];      // 8704B  (l3 tree aliases res)
    int b = blockIdx.y;
    int n0 = blockIdx.x * 64;
    int t = threadIdx.x;
    int nrem = NPTS - n0; if (nrem > 64) nrem = 64;

    float* l3 = res;
    if (t < 96) {
        int c = t >> 5, l = t & 31;
        const float* q = wsf + 2048 + (size_t)(b * 3 + c) * 256 + l * 8;
        float a  = __fadd_rn(__fadd_rn(q[0], q[1]), __fadd_rn(q[2], q[3]));
        float b2 = __fadd_rn(__fadd_rn(q[4], q[5]), __fadd_rn(q[6], q[7]));
        l3[c * 32 + l] = __fadd_rn(a, b2);
    }
    __syncthreads();
    for (int m = 16; m >= 1; m >>= 1) {
        float v = 0.0f;
        int c = t >> 5, l = t & 31;
        if (t < 96 && l < m) v = __fadd_rn(l3[c * 32 + 2 * l], l3[c * 32 + 2 * l + 1]);
        __syncthreads();
        if (t < 96 && l < m) l3[c * 32 + l] = v;
        __syncthreads();
    }
    float dn0 = __fmul_rn(4.0f, sqrtf(l3[0]  / 799999.0f));
    float dn1 = __fmul_rn(4.0f, sqrtf(l3[32] / 799999.0f));
    float dn2 = __fmul_rn(4.0f, sqrtf(l3[64] / 799999.0f));
    __syncthreads();

    const unsigned int* gdwp = (const unsigned int*)(wsf + 8192);
    for (int i = t; i < NCELL * 32; i += 256) dwp[i] = gdwp[i];
    const float* xb = xyz + (size_t)b * 3 * NPTS;
    if (t < 192) {
        int c = t >> 6, jx = t & 63;
        if (jx < nrem) ctr[c][jx] = xb[c * NPTS + n0 + jx];
    }
    const int* ib = idx + ((size_t)b * NPTS + n0) * KNN;
    __syncthreads();

    for (int i = t; i < nrem * KNN; i += 256) {
        int p = i >> 4;
        int jx = ib[i];
        float sx = __fsub_rn(xb[jx],            ctr[0][p]) / dn0;
        float sy = __fsub_rn(xb[NPTS + jx],     ctr[1][p]) / dn1;
        float sz = __fsub_rn(xb[2 * NPTS + jx], ctr[2][p]) / dn2;
        celllds[i] = (unsigned char)((to_cell32(sz) * 5 + to_cell32(sy)) * 5 + to_cell32(sx));
    }
    __syncthreads();

    int w = t >> 6, h = (t >> 5) & 1, u = t & 31;
    int o0 = 2 * u, o1 = 2 * u + 1;
    float cb0 = cb[o0], cb1 = cb[o1];
    const unsigned short* gbp = g + (size_t)b * NPTS * C2;
    float* ob = out + (size_t)b * 128 * NPTS;

    #pragma unroll 1
    for (int chunk = 0; chunk < 4; ++chunk) {
        int pbase = chunk * 16;
        #pragma unroll 1
        for (int i = 0; i < 2; ++i) {
            int p = pbase + i * 8 + w * 2 + h;
            if (p < nrem) {
                const int* row = ib + p * KNN;
                unsigned int gnv = *(const unsigned int*)(gbp + (size_t)(n0 + p) * C2 + o0);
                float gn0 = bflo(gnv), gn1 = bfhi(gnv);
                int cell0 = celllds[p * KNN];
                unsigned int dp0 = dwp[cell0 * 32 + u];
                float k00 = bflo(dp0), k01 = bfhi(dp0);
                float ws0 = 0, ws1 = 0, gs0 = 0, gs1 = 0, sk0 = 0, sk1 = 0;
                #pragma unroll
                for (int k = 1; k < 16; ++k) {
                    int jj   = row[k];                         // broadcast, L1-hot
                    int cell = celllds[p * KNN + k];
                    unsigned int gv = *(const unsigned int*)(gbp + (size_t)jj * C2 + o0);
                    unsigned int dp = dwp[cell * 32 + u];
                    float g0 = bflo(gv), g1 = bfhi(gv);
                    float kw0 = bflo(dp), kw1 = bfhi(dp);
                    ws0 = fmaf(kw0, g0, ws0); ws1 = fmaf(kw1, g1, ws1);
                    gs0 += g0; gs1 += g1; sk0 += kw0; sk1 += kw1;
                }
                int pl = p & 15;
                res[o0 * 17 + pl]        = cb0 * (k00 + sk0) + gn0 * (k00 - sk0) + ws0;
                res[o1 * 17 + pl]        = cb1 * (k01 + sk1) + gn1 * (k01 - sk1) + ws1;
                res[(64 + o0) * 17 + pl] = cb0 + 0.0625f * (gs0 - 14.0f * gn0);
                res[(64 + o1) * 17 + pl] = cb1 + 0.0625f * (gs1 - 14.0f * gn1);
            }
        }
        __syncthreads();
        int rl = t >> 4;
        int jn = t & 15;
        int ncol = nrem - pbase; if (ncol > 16) ncol = 16;
        if (jn < ncol) {
            for (int r2 = rl; r2 < 128; r2 += 16)
                ob[(size_t)r2 * NPTS + n0 + pbase + jn] = res[r2 * 17 + jn];
        }
        __syncthreads();
    }
}

extern "C" void kernel_launch(void* const* d_in, const int* in_sizes, int n_in,
                              void* d_out, int out_size, void* d_ws, size_t ws_size,
                              hipStream_t stream) {
    const float* xyz   = (const float*)d_in[0];
    const float* fea   = (const float*)d_in[1];
    const int*   knn   = (const int*)d_in[2];
    const float* convw = (const float*)d_in[3];
    const float* convb = (const float*)d_in[4];
    const float* convdw= (const float*)d_in[5];
    float* out = (float*)d_out;
    float* wsf = (float*)d_ws;
    unsigned short* g = (unsigned short*)(wsf + 16384);
    float* relc = out;               // 4.8M floats scratch, fully overwritten by kmain

    kpw1  <<<dim3(256, BATCH), 256, 0, stream>>>(xyz, knn, relc, wsf);
    kfuse2<<<1564 + 1536 + 16, 256, 0, stream>>>(fea, convw, convdw, g, relc, wsf);
    kmain <<<dim3(782, BATCH), 256, 0, stream>>>(xyz, knn, convb, g, wsf, out);
}